// Round 1
// baseline (112.643 us; speedup 1.0000x reference)
//
#include <hip/hip_runtime.h>

// FactoredBlock: out[n,:] = sum_{k in row n} values[k] * weights[f_table[active_idx[k]], :]
// batch_idx sorted -> contiguous per-row ranges found via binary search.
// 1 wave per output row; lane l owns cols [4l, 4l+4); float4 weight loads (L2-resident).

#define OUT_COLS 256
#define WAVES_PER_BLOCK 4
#define BLOCK_THREADS (WAVES_PER_BLOCK * 64)

__global__ __launch_bounds__(BLOCK_THREADS, 8)
void factored_block_kernel(const int* __restrict__ batch_idx,
                           const int* __restrict__ active_idx,
                           const float* __restrict__ values,
                           const int* __restrict__ f_table,
                           const float* __restrict__ weights,
                           float* __restrict__ out,
                           int nnz, int N)
{
    const int wave = threadIdx.x >> 6;
    const int lane = threadIdx.x & 63;
    const int row  = blockIdx.x * WAVES_PER_BLOCK + wave;
    if (row >= N) return;

    // Two interleaved binary searches (lower_bound(row), lower_bound(row+1)).
    // All lanes run them redundantly; wave-uniform control flow, loads broadcast.
    int lo1 = 0, hi1 = nnz, lo2 = 0, hi2 = nnz;
    while ((lo1 < hi1) | (lo2 < hi2)) {
        if (lo1 < hi1) {
            int mid = (lo1 + hi1) >> 1;
            if (batch_idx[mid] < row) lo1 = mid + 1; else hi1 = mid;
        }
        if (lo2 < hi2) {
            int mid = (lo2 + hi2) >> 1;
            if (batch_idx[mid] < row + 1) lo2 = mid + 1; else hi2 = mid;
        }
    }
    const int start = lo1;
    const int end   = lo2;

    float4 acc = make_float4(0.f, 0.f, 0.f, 0.f);
    const float* __restrict__ wcol = weights + (lane << 2);  // + f*256 per nnz

    // Chunks of 64 nnz (avg row has ~32; >64 essentially never, but handled).
    for (int base = start; base < end; base += 64) {
        const int cnt = min(end - base, 64);
        float v_l = 0.f;
        int   f_l = 0;
        if (lane < cnt) {
            const int k = base + lane;
            v_l = values[k];
            f_l = f_table[active_idx[k]];
        }
        for (int j = 0; j < cnt; ++j) {
            const float v = __shfl(v_l, j);
            const int   f = __shfl(f_l, j);
            const float4 w = *(const float4*)(wcol + f * OUT_COLS);
            acc.x = fmaf(v, w.x, acc.x);
            acc.y = fmaf(v, w.y, acc.y);
            acc.z = fmaf(v, w.z, acc.z);
            acc.w = fmaf(v, w.w, acc.w);
        }
    }

    *(float4*)(out + row * OUT_COLS + (lane << 2)) = acc;
}

extern "C" void kernel_launch(void* const* d_in, const int* in_sizes, int n_in,
                              void* d_out, int out_size, void* d_ws, size_t ws_size,
                              hipStream_t stream) {
    const int*   batch_idx  = (const int*)d_in[0];
    const int*   active_idx = (const int*)d_in[1];
    const float* values     = (const float*)d_in[2];
    const int*   f_table    = (const int*)d_in[3];
    const float* weights    = (const float*)d_in[4];
    float*       out        = (float*)d_out;

    const int nnz = in_sizes[0];
    const int N   = out_size / OUT_COLS;  // 16384

    const int grid = (N + WAVES_PER_BLOCK - 1) / WAVES_PER_BLOCK;
    factored_block_kernel<<<grid, BLOCK_THREADS, 0, stream>>>(
        batch_idx, active_idx, values, f_table, weights, out, nnz, N);
}

// Round 2
// 96.236 us; speedup vs baseline: 1.1705x; 1.1705x over previous
//
#include <hip/hip_runtime.h>

// FactoredBlock: out[n,:] = sum_{k in row n} values[k] * weights[f_table[active_idx[k]], :]
// batch_idx sorted. Three-phase:
//   build_kernel: CSR offsets[N+1] + fused (f, value) pairs -> d_ws
//   gemm_kernel:  1 wave/row, lane owns 4 cols, unroll-8 weight loads (L2-resident weights)
// Fallback to binary-search kernel if d_ws too small (shouldn't happen: need ~4.3 MB).

#define OUT_COLS 256
#define WAVES_PER_BLOCK 4
#define BLOCK_THREADS (WAVES_PER_BLOCK * 64)

// ---------------- phase A: offsets + pairs ----------------
__global__ __launch_bounds__(256)
void build_kernel(const int* __restrict__ batch_idx,
                  const int* __restrict__ active_idx,
                  const float* __restrict__ values,
                  const int* __restrict__ f_table,
                  int* __restrict__ offsets,      // [N+1]
                  int2* __restrict__ pairs,       // [nnz] {f, bits(v)} or null
                  int nnz, int N)
{
    const int k = blockIdx.x * blockDim.x + threadIdx.x;
    if (k >= nnz) return;
    const int r  = batch_idx[k];
    const int rp = (k == 0) ? -1 : batch_idx[k - 1];
    for (int row = rp + 1; row <= r; ++row) offsets[row] = k;   // lower_bound fill
    if (k == nnz - 1)
        for (int row = r + 1; row <= N; ++row) offsets[row] = nnz;
    if (pairs)
        pairs[k] = make_int2(f_table[active_idx[k]], __float_as_int(values[k]));
}

// ---------------- phase B: accumulate ----------------
__global__ __launch_bounds__(BLOCK_THREADS, 8)
void gemm_kernel(const int* __restrict__ offsets,
                 const int2* __restrict__ pairs,
                 const float* __restrict__ weights,
                 float* __restrict__ out, int N)
{
    const int lane = threadIdx.x & 63;
    const int row  = blockIdx.x * WAVES_PER_BLOCK + (threadIdx.x >> 6);
    if (row >= N) return;

    // wave-uniform bounds -> enables scalar (s_load) pair fetches
    const int start = __builtin_amdgcn_readfirstlane(offsets[row]);
    const int end   = __builtin_amdgcn_readfirstlane(offsets[row + 1]);

    float4 acc = make_float4(0.f, 0.f, 0.f, 0.f);
    const float* __restrict__ wbase = weights + (lane << 2);

    int k = start;
    for (; k + 8 <= end; k += 8) {
        int2 p[8];
#pragma unroll
        for (int j = 0; j < 8; ++j) p[j] = pairs[k + j];
        float4 w[8];
#pragma unroll
        for (int j = 0; j < 8; ++j)
            w[j] = *(const float4*)(wbase + p[j].x * OUT_COLS);
#pragma unroll
        for (int j = 0; j < 8; ++j) {
            const float v = __int_as_float(p[j].y);
            acc.x = fmaf(v, w[j].x, acc.x);
            acc.y = fmaf(v, w[j].y, acc.y);
            acc.z = fmaf(v, w[j].z, acc.z);
            acc.w = fmaf(v, w[j].w, acc.w);
        }
    }
    for (; k < end; ++k) {
        const int2 p = pairs[k];
        const float v = __int_as_float(p.y);
        const float4 w = *(const float4*)(wbase + p.x * OUT_COLS);
        acc.x = fmaf(v, w.x, acc.x);
        acc.y = fmaf(v, w.y, acc.y);
        acc.z = fmaf(v, w.z, acc.z);
        acc.w = fmaf(v, w.w, acc.w);
    }

    *(float4*)(out + row * OUT_COLS + (lane << 2)) = acc;
}

// ---------------- fallback (round-1 kernel), used only if ws too small ----------------
__global__ __launch_bounds__(BLOCK_THREADS, 8)
void fallback_kernel(const int* __restrict__ batch_idx,
                     const int* __restrict__ active_idx,
                     const float* __restrict__ values,
                     const int* __restrict__ f_table,
                     const float* __restrict__ weights,
                     float* __restrict__ out,
                     int nnz, int N)
{
    const int wave = threadIdx.x >> 6;
    const int lane = threadIdx.x & 63;
    const int row  = blockIdx.x * WAVES_PER_BLOCK + wave;
    if (row >= N) return;

    int lo1 = 0, hi1 = nnz, lo2 = 0, hi2 = nnz;
    while ((lo1 < hi1) | (lo2 < hi2)) {
        if (lo1 < hi1) { int m = (lo1 + hi1) >> 1; if (batch_idx[m] < row) lo1 = m + 1; else hi1 = m; }
        if (lo2 < hi2) { int m = (lo2 + hi2) >> 1; if (batch_idx[m] < row + 1) lo2 = m + 1; else hi2 = m; }
    }
    float4 acc = make_float4(0.f, 0.f, 0.f, 0.f);
    const float* __restrict__ wcol = weights + (lane << 2);
    for (int base = lo1; base < lo2; base += 64) {
        const int cnt = min(lo2 - base, 64);
        float v_l = 0.f; int f_l = 0;
        if (lane < cnt) { const int k = base + lane; v_l = values[k]; f_l = f_table[active_idx[k]]; }
        for (int j = 0; j < cnt; ++j) {
            const float v = __shfl(v_l, j);
            const int   f = __shfl(f_l, j);
            const float4 w = *(const float4*)(wcol + f * OUT_COLS);
            acc.x = fmaf(v, w.x, acc.x);
            acc.y = fmaf(v, w.y, acc.y);
            acc.z = fmaf(v, w.z, acc.z);
            acc.w = fmaf(v, w.w, acc.w);
        }
    }
    *(float4*)(out + row * OUT_COLS + (lane << 2)) = acc;
}

extern "C" void kernel_launch(void* const* d_in, const int* in_sizes, int n_in,
                              void* d_out, int out_size, void* d_ws, size_t ws_size,
                              hipStream_t stream) {
    const int*   batch_idx  = (const int*)d_in[0];
    const int*   active_idx = (const int*)d_in[1];
    const float* values     = (const float*)d_in[2];
    const int*   f_table    = (const int*)d_in[3];
    const float* weights    = (const float*)d_in[4];
    float*       out        = (float*)d_out;

    const int nnz = in_sizes[0];
    const int N   = out_size / OUT_COLS;  // 16384

    const size_t off_bytes   = (size_t)(N + 1) * sizeof(int);
    const size_t pairs_off   = (off_bytes + 15) & ~(size_t)15;
    const size_t need_pairs  = pairs_off + (size_t)nnz * sizeof(int2);

    const int grid_rows = (N + WAVES_PER_BLOCK - 1) / WAVES_PER_BLOCK;

    if (ws_size >= need_pairs) {
        int*  offsets = (int*)d_ws;
        int2* pairs   = (int2*)((char*)d_ws + pairs_off);
        const int grid_nnz = (nnz + 255) / 256;
        build_kernel<<<grid_nnz, 256, 0, stream>>>(batch_idx, active_idx, values,
                                                   f_table, offsets, pairs, nnz, N);
        gemm_kernel<<<grid_rows, BLOCK_THREADS, 0, stream>>>(offsets, pairs, weights, out, N);
    } else {
        fallback_kernel<<<grid_rows, BLOCK_THREADS, 0, stream>>>(
            batch_idx, active_idx, values, f_table, weights, out, nnz, N);
    }
}